// Round 2
// baseline (360.720 us; speedup 1.0000x reference)
//
#include <hip/hip_runtime.h>

#define EPS 1e-10f

// Problem shape (fixed by setup_inputs): [B, C, F, T] = [32, 2, 257, 2000]
constexpr int B  = 32;
constexpr int CF = 514;   // C*F = 2*257
constexpr int T  = 2000;
constexpr int T4 = T / 4; // 500 float4 per row

// ---------------------------------------------------------------------------
// Kernel 1: frame_mean[b][t] = mean_{cf} x[b][cf][t]
// block = (64 t-lanes, 8 cf-groups); each wave reads 64 consecutive t floats
// per cf iteration (coalesced, 256B-aligned). LDS reduce across the 8 groups.
// grid = (T/64, B) = (32, 32) -> 1024 blocks * 8 waves = full occupancy.
// ---------------------------------------------------------------------------
__global__ __launch_bounds__(512) void k_frame_mean(const float* __restrict__ x,
                                                    float* __restrict__ fm) {
    __shared__ float lds[8][64];
    const int t  = blockIdx.x * 64 + threadIdx.x;   // T=2000 < 32*64=2048
    const int b  = blockIdx.y;
    const int ty = threadIdx.y;

    float s = 0.0f;
    if (t < T) {
        const float* p = x + ((size_t)b * CF + ty) * T + t;
        #pragma unroll 4
        for (int cf = ty; cf < CF; cf += 8) {
            s += *p;
            p += 8 * (size_t)T;
        }
    }
    lds[ty][threadIdx.x] = s;
    __syncthreads();
    if (ty == 0 && t < T) {
        float tot = lds[0][threadIdx.x];
        #pragma unroll
        for (int k = 1; k < 8; ++k) tot += lds[k][threadIdx.x];
        fm[(size_t)b * T + t] = tot / (float)CF;
    }
}

// ---------------------------------------------------------------------------
// Kernel 2: EMA scan over T per batch. One lane per batch (32 active lanes
// of one wave). a[t] = min((t-1)/(t+1), alpha) computed with IEEE fp32
// division every step, exactly like the reference; the division is off the
// mu dependence chain so it hides under the serial fma latency.
// ---------------------------------------------------------------------------
__global__ __launch_bounds__(64) void k_scan(const float* __restrict__ fm,
                                             const int* __restrict__ d_sl,
                                             float* __restrict__ mu_out) {
    const int b = threadIdx.x;
    if (b >= B) return;
    const int sl = d_sl[0];
    const float alpha = (float)((double)(sl - 1) / (double)(sl + 1));

    const float* m = fm + (size_t)b * T;
    float*       o = mu_out + (size_t)b * T;

    float mu = 0.0f;
    for (int t = 0; t < T; ++t) {
        const float ft = (float)t;
        const float a  = fminf((ft - 1.0f) / (ft + 1.0f), alpha);
        mu = a * mu + (1.0f - a) * m[t];
        o[t] = mu;
    }
}

// ---------------------------------------------------------------------------
// Kernel 3: out[b][cf][t] = x[b][cf][t] / (mu[b][t] + EPS), float4-vectorized.
// grid = (2, B*CF); each block covers 256 float4 of one row. mu row (8 KB)
// is L1/L2-resident across the 514 rows of a batch.
// ---------------------------------------------------------------------------
__global__ __launch_bounds__(256) void k_norm(const float4* __restrict__ x,
                                              const float* __restrict__ mu,
                                              float4* __restrict__ out) {
    const int t4  = blockIdx.x * 256 + threadIdx.x;
    if (t4 >= T4) return;
    const int row = blockIdx.y;       // b*CF + cf
    const int b   = row / CF;

    const size_t idx = (size_t)row * T4 + t4;
    const float4 v  = x[idx];
    const float4 m4 = *(const float4*)(mu + (size_t)b * T + (size_t)t4 * 4);

    float4 r;
    r.x = v.x / (m4.x + EPS);
    r.y = v.y / (m4.y + EPS);
    r.z = v.z / (m4.z + EPS);
    r.w = v.w / (m4.w + EPS);
    out[idx] = r;
}

// ---------------------------------------------------------------------------
extern "C" void kernel_launch(void* const* d_in, const int* in_sizes, int n_in,
                              void* d_out, int out_size, void* d_ws, size_t ws_size,
                              hipStream_t stream) {
    const float* x    = (const float*)d_in[0];
    const int*   d_sl = (const int*)d_in[1];
    float*       out  = (float*)d_out;

    // workspace layout: fm [B*T] floats, mu [B*T] floats  (512 KB total)
    float* fm = (float*)d_ws;
    float* mu = fm + (size_t)B * T;

    // Kernel 1: per-frame mean
    {
        dim3 grid((T + 63) / 64, B);
        dim3 block(64, 8);
        k_frame_mean<<<grid, block, 0, stream>>>(x, fm);
    }
    // Kernel 2: EMA scan (tiny, latency-bound)
    {
        k_scan<<<1, 64, 0, stream>>>(fm, d_sl, mu);
    }
    // Kernel 3: normalize
    {
        dim3 grid((T4 + 255) / 256, B * CF);
        dim3 block(256);
        k_norm<<<grid, block, 0, stream>>>((const float4*)x, mu, (float4*)out);
    }
}

// Round 3
// 311.850 us; speedup vs baseline: 1.1567x; 1.1567x over previous
//
#include <hip/hip_runtime.h>

#define EPS 1e-10f

// Problem shape (fixed by setup_inputs): [B, C, F, T] = [32, 2, 257, 2000]
constexpr int B  = 32;
constexpr int CF = 514;   // C*F = 2*257
constexpr int T  = 2000;
constexpr int T4 = T / 4; // 500 float4 per row

// ---------------------------------------------------------------------------
// Kernel 1: frame_mean[b][t] = mean_{cf} x[b][cf][t]
// block = (64 t-lanes, 8 cf-groups); each wave reads 64 consecutive t floats
// per cf iteration (coalesced, 256B-aligned). LDS reduce across the 8 groups.
// Memory-bound: 131.6 MB read -> ~21 us floor.
// ---------------------------------------------------------------------------
__global__ __launch_bounds__(512) void k_frame_mean(const float* __restrict__ x,
                                                    float* __restrict__ fm) {
    __shared__ float lds[8][64];
    const int t  = blockIdx.x * 64 + threadIdx.x;   // T=2000 < 32*64=2048
    const int b  = blockIdx.y;
    const int ty = threadIdx.y;

    float s = 0.0f;
    if (t < T) {
        const float* p = x + ((size_t)b * CF + ty) * T + t;
        #pragma unroll 4
        for (int cf = ty; cf < CF; cf += 8) {
            s += *p;
            p += 8 * (size_t)T;
        }
    }
    lds[ty][threadIdx.x] = s;
    __syncthreads();
    if (ty == 0 && t < T) {
        float tot = lds[0][threadIdx.x];
        #pragma unroll
        for (int k = 1; k < 8; ++k) tot += lds[k][threadIdx.x];
        fm[(size_t)b * T + t] = tot / (float)CF;
    }
}

// ---------------------------------------------------------------------------
// Kernel 2: EMA scan, one lane per batch (32 active lanes of one wave).
// Round-2 counters: 124 us — serial load->fma->store left L2 latency on the
// critical path and per-t IEEE divides cost ~24cy/t of issue.
// Fix: (a) 16-element chunks, double-buffered float4 register loads so load
// latency overlaps the fma chain; (b) chunk-uniform phase split: for chunks
// with c > sl, min((t-1)/(t+1), alpha) == alpha exactly (real gap at t=sl+1
// is 5.3e-5 >> fp32 ulp 6e-8), so no divide at all on 90% of chunks.
// ---------------------------------------------------------------------------
__global__ __launch_bounds__(64) void k_scan(const float* __restrict__ fm,
                                             const int* __restrict__ d_sl,
                                             float* __restrict__ mu_out) {
    const int b = threadIdx.x;
    if (b >= B) return;
    const int sl = d_sl[0];
    // matches Python: (sl-1)/(sl+1) in double, rounded once to fp32
    const float alpha = (float)((double)(sl - 1) / (double)(sl + 1));
    const float oma   = 1.0f - alpha;

    const float* __restrict__ m = fm + (size_t)b * T;
    float* __restrict__ o = mu_out + (size_t)b * T;

    float mu = 0.0f;
    float4 A0, A1, A2, A3, Bc0, Bc1, Bc2, Bc3;

#define LDCH(P, c) do {                              \
        P##0 = *(const float4*)(m + (c));            \
        P##1 = *(const float4*)(m + (c) + 4);        \
        P##2 = *(const float4*)(m + (c) + 8);        \
        P##3 = *(const float4*)(m + (c) + 12);       \
    } while (0)

#define PROC(P, cc) do {                                                     \
        float v[16];                                                         \
        *(float4*)(v + 0)  = P##0; *(float4*)(v + 4)  = P##1;                \
        *(float4*)(v + 8)  = P##2; *(float4*)(v + 12) = P##3;                \
        float r[16];                                                         \
        if ((cc) > sl) {   /* whole chunk uses constant alpha */             \
            _Pragma("unroll")                                                \
            for (int i = 0; i < 16; ++i) {                                   \
                mu = alpha * mu + oma * v[i];                                \
                r[i] = mu;                                                   \
            }                                                                \
        } else {           /* exact per-t formula incl. min */               \
            _Pragma("unroll")                                                \
            for (int i = 0; i < 16; ++i) {                                   \
                const float ft = (float)((cc) + i);                          \
                const float a  = fminf((ft - 1.0f) / (ft + 1.0f), alpha);    \
                mu = a * mu + (1.0f - a) * v[i];                             \
                r[i] = mu;                                                   \
            }                                                                \
        }                                                                    \
        *(float4*)(o + (cc))      = *(float4*)(r + 0);                       \
        *(float4*)(o + (cc) + 4)  = *(float4*)(r + 4);                       \
        *(float4*)(o + (cc) + 8)  = *(float4*)(r + 8);                       \
        *(float4*)(o + (cc) + 12) = *(float4*)(r + 12);                      \
    } while (0)

    LDCH(A, 0);
    // T = 2000 = 62 pairs of 16 + one final 16-chunk (c = 1984)
    for (int c = 0; c < T; c += 32) {
        if (c + 16 < T) LDCH(Bc, c + 16);   // prefetch next chunk
        PROC(A, c);
        if (c + 32 < T) LDCH(A, c + 32);    // prefetch chunk after
        if (c + 16 < T) PROC(Bc, c + 16);
    }
#undef LDCH
#undef PROC
}

// ---------------------------------------------------------------------------
// Kernel 3: out[b][cf][t] = x[b][cf][t] / (mu[b][t] + EPS), float4-vectorized.
// grid = (2, B*CF). Memory-bound (263 MB traffic): the 4 IEEE divides/thread
// (~72 cy issue/wave) hide under ~200 cy of memory per wave.
// ---------------------------------------------------------------------------
__global__ __launch_bounds__(256) void k_norm(const float4* __restrict__ x,
                                              const float* __restrict__ mu,
                                              float4* __restrict__ out) {
    const int t4  = blockIdx.x * 256 + threadIdx.x;
    if (t4 >= T4) return;
    const int row = blockIdx.y;       // b*CF + cf
    const int b   = row / CF;

    const size_t idx = (size_t)row * T4 + t4;
    const float4 v  = x[idx];
    const float4 m4 = *(const float4*)(mu + (size_t)b * T + (size_t)t4 * 4);

    float4 r;
    r.x = v.x / (m4.x + EPS);
    r.y = v.y / (m4.y + EPS);
    r.z = v.z / (m4.z + EPS);
    r.w = v.w / (m4.w + EPS);
    out[idx] = r;
}

// ---------------------------------------------------------------------------
extern "C" void kernel_launch(void* const* d_in, const int* in_sizes, int n_in,
                              void* d_out, int out_size, void* d_ws, size_t ws_size,
                              hipStream_t stream) {
    const float* x    = (const float*)d_in[0];
    const int*   d_sl = (const int*)d_in[1];
    float*       out  = (float*)d_out;

    // workspace layout: fm [B*T] floats, mu [B*T] floats  (512 KB total)
    float* fm = (float*)d_ws;
    float* mu = fm + (size_t)B * T;

    // Kernel 1: per-frame mean
    {
        dim3 grid((T + 63) / 64, B);
        dim3 block(64, 8);
        k_frame_mean<<<grid, block, 0, stream>>>(x, fm);
    }
    // Kernel 2: EMA scan (single wave, latency-bound — now chunked+dbuf)
    {
        k_scan<<<1, 64, 0, stream>>>(fm, d_sl, mu);
    }
    // Kernel 3: normalize
    {
        dim3 grid((T4 + 255) / 256, B * CF);
        dim3 block(256);
        k_norm<<<grid, block, 0, stream>>>((const float4*)x, mu, (float4*)out);
    }
}

// Round 4
// 258.428 us; speedup vs baseline: 1.3958x; 1.2067x over previous
//
#include <hip/hip_runtime.h>

#define EPS 1e-10f

// Problem shape (fixed by setup_inputs): [B, C, F, T] = [32, 2, 257, 2000]
constexpr int B  = 32;
constexpr int CF = 514;   // C*F = 2*257
constexpr int T  = 2000;
constexpr int T4 = T / 4; // 500 float4 per row

// ---------------------------------------------------------------------------
// Kernel 1: frame_mean[b][t] = mean_{cf} x[b][cf][t]
// block = (64 t-lanes, 8 cf-groups); each wave reads 64 consecutive t floats
// per cf iteration (coalesced, 256B-aligned). LDS reduce across the 8 groups.
// Memory-bound: 131.6 MB read -> ~21 us floor.
// ---------------------------------------------------------------------------
__global__ __launch_bounds__(512) void k_frame_mean(const float* __restrict__ x,
                                                    float* __restrict__ fm) {
    __shared__ float lds[8][64];
    const int t  = blockIdx.x * 64 + threadIdx.x;   // T=2000 < 32*64=2048
    const int b  = blockIdx.y;
    const int ty = threadIdx.y;

    float s = 0.0f;
    if (t < T) {
        const float* p = x + ((size_t)b * CF + ty) * T + t;
        #pragma unroll 4
        for (int cf = ty; cf < CF; cf += 8) {
            s += *p;
            p += 8 * (size_t)T;
        }
    }
    lds[ty][threadIdx.x] = s;
    __syncthreads();
    if (ty == 0 && t < T) {
        float tot = lds[0][threadIdx.x];
        #pragma unroll
        for (int k = 1; k < 8; ++k) tot += lds[k][threadIdx.x];
        fm[(size_t)b * T + t] = tot / (float)CF;
    }
}

// ---------------------------------------------------------------------------
// Kernel 2: parallel EMA scan. mu[t] = a[t]*mu[t-1] + (1-a[t])*m[t] is an
// affine recurrence; affine maps compose associatively, so: one wave per
// batch, lane l owns the contiguous chunk t in [32l, 32l+32):
//   pass 1: serially compose the chunk into (A,B)  (mu_out = A*mu_in + B)
//   wave-level inclusive __shfl_up scan of affine pairs (6 steps)
//   pass 2: apply incoming exclusive prefix (mu_in = B_excl since mu0 = 0),
//           recompute serially, store.
// Round-3 lesson: the serial 1-wave scan was ~75 us because fm was written
// by blocks on all 8 XCDs -> every load missed local L2 (~600-900 cy) and
// 1-chunk prefetch couldn't cover it. The parallel version has 32 concurrent
// waves and ~650 cy of dependent work total.
// a[t] keeps the exact reference formula: fminf((t-1)/(t+1), alpha), IEEE div.
// ---------------------------------------------------------------------------
__global__ __launch_bounds__(256) void k_scan_par(const float* __restrict__ fm,
                                                  const int* __restrict__ d_sl,
                                                  float* __restrict__ mu_out) {
    const int wave = threadIdx.x >> 6;           // 0..3
    const int lane = threadIdx.x & 63;
    const int b    = blockIdx.x * 4 + wave;      // grid 8 -> b in [0,32)
    if (b >= B) return;

    const int sl = d_sl[0];
    const float alpha = (float)((double)(sl - 1) / (double)(sl + 1));

    const float* __restrict__ m = fm + (size_t)b * T;
    float* __restrict__ o = mu_out + (size_t)b * T;

    const int t0 = lane * 32;                    // lanes 0..61 full, 62 partial, 63 empty

    // Load chunk (float4 when fully in range; guarded scalar tail otherwise).
    float v[32];
    if (t0 + 32 <= T) {
        #pragma unroll
        for (int j = 0; j < 8; ++j)
            *(float4*)(v + 4 * j) = *(const float4*)(m + t0 + 4 * j);
    } else {
        #pragma unroll
        for (int j = 0; j < 32; ++j)
            v[j] = (t0 + j < T) ? m[t0 + j] : 0.0f;
    }

    // Pass 1: compose chunk into affine (A, Bv). Inactive t -> identity (a=1, v=0).
    float A = 1.0f, Bv = 0.0f;
    #pragma unroll
    for (int i = 0; i < 32; ++i) {
        const int t = t0 + i;
        const float ft = (float)t;
        const float a  = (t < T) ? fminf((ft - 1.0f) / (ft + 1.0f), alpha) : 1.0f;
        const float vv = (t < T) ? v[i] : 0.0f;
        Bv = a * Bv + (1.0f - a) * vv;
        A  = a * A;
    }

    // Inclusive wave scan of affine pairs: later ∘ earlier.
    float pA = A, pB = Bv;
    #pragma unroll
    for (int d = 1; d < 64; d <<= 1) {
        const float uA = __shfl_up(pA, d);
        const float uB = __shfl_up(pB, d);
        if (lane >= d) {
            pB = pA * uB + pB;   // B_comb = A_later*B_earlier + B_later
            pA = pA * uA;
        }
    }

    // Incoming mu for this lane = exclusive prefix applied to mu0=0 -> B_excl.
    const float eB = __shfl_up(pB, 1);
    float mu = (lane == 0) ? 0.0f : eB;

    // Pass 2: serial recompute with true incoming mu; store.
    #pragma unroll
    for (int i = 0; i < 32; ++i) {
        const int t = t0 + i;
        if (t < T) {
            const float ft = (float)t;
            const float a  = fminf((ft - 1.0f) / (ft + 1.0f), alpha);
            mu = a * mu + (1.0f - a) * v[i];
            o[t] = mu;
        }
    }
}

// ---------------------------------------------------------------------------
// Kernel 3: out[b][cf][t] = x[b][cf][t] / (mu[b][t] + EPS), float4-vectorized.
// grid = (2, B*CF). Memory-bound (263 MB traffic): the 4 IEEE divides/thread
// (~80 cy issue/wave) hide under ~400 cy of memory per wave.
// ---------------------------------------------------------------------------
__global__ __launch_bounds__(256) void k_norm(const float4* __restrict__ x,
                                              const float* __restrict__ mu,
                                              float4* __restrict__ out) {
    const int t4  = blockIdx.x * 256 + threadIdx.x;
    if (t4 >= T4) return;
    const int row = blockIdx.y;       // b*CF + cf
    const int b   = row / CF;

    const size_t idx = (size_t)row * T4 + t4;
    const float4 v  = x[idx];
    const float4 m4 = *(const float4*)(mu + (size_t)b * T + (size_t)t4 * 4);

    float4 r;
    r.x = v.x / (m4.x + EPS);
    r.y = v.y / (m4.y + EPS);
    r.z = v.z / (m4.z + EPS);
    r.w = v.w / (m4.w + EPS);
    out[idx] = r;
}

// ---------------------------------------------------------------------------
extern "C" void kernel_launch(void* const* d_in, const int* in_sizes, int n_in,
                              void* d_out, int out_size, void* d_ws, size_t ws_size,
                              hipStream_t stream) {
    const float* x    = (const float*)d_in[0];
    const int*   d_sl = (const int*)d_in[1];
    float*       out  = (float*)d_out;

    // workspace layout: fm [B*T] floats, mu [B*T] floats  (512 KB total)
    float* fm = (float*)d_ws;
    float* mu = fm + (size_t)B * T;

    // Kernel 1: per-frame mean
    {
        dim3 grid((T + 63) / 64, B);
        dim3 block(64, 8);
        k_frame_mean<<<grid, block, 0, stream>>>(x, fm);
    }
    // Kernel 2: parallel EMA scan (32 waves, affine prefix scan)
    {
        k_scan_par<<<8, 256, 0, stream>>>(fm, d_sl, mu);
    }
    // Kernel 3: normalize
    {
        dim3 grid((T4 + 255) / 256, B * CF);
        dim3 block(256);
        k_norm<<<grid, block, 0, stream>>>((const float4*)x, mu, (float4*)out);
    }
}